// Round 14
// baseline (242.199 us; speedup 1.0000x reference)
//
#include <hip/hip_runtime.h>
#include <math.h>

#define C 256
#define S 4096
#define NH 8
#define NSG 16        // s-groups per bn (256 s each) = Mp partial groups
#define NSTRIP 64     // LP/ZP strips per bn (16 sg x 4 waves)
#define EPS 1e-5f
#define SCALE 0.17677669529663687f   // 1/sqrt(32)

#define PTS 272       // ptT LDS row stride (ushorts)

// workspace layout (float offsets)
#define OFF_GWP  0                 // 64*256*4 uints = 65536
#define OFF_G    65536             // 512
#define OFF_BC   66048             // 512
#define OFF_PART 66560             // 8*64*2*4096 = 4194304 (per-chunk sum/sq planes)
#define OFF_RM   4260864           // 64*2*4096 = 524288 (rstd, mur planes)
#define OFF_LP   4785152           // 32768
#define OFF_ZP   4817920           // 32768
#define OFF_MP   4850688           // 16*64*256*8 = 2097152

typedef __attribute__((ext_vector_type(8))) short short8;
typedef __attribute__((ext_vector_type(4))) float f32x4;

__device__ __forceinline__ float bf_lo(unsigned int u) {
    return __builtin_bit_cast(float, u << 16);
}
__device__ __forceinline__ float bf_hi(unsigned int u) {
    return __builtin_bit_cast(float, u & 0xffff0000u);
}
__device__ __forceinline__ unsigned int bf_pack(float a, float b) {
    unsigned int ua = (__builtin_bit_cast(unsigned int, a) + 0x8000u) >> 16;
    unsigned int ub = (__builtin_bit_cast(unsigned int, b) + 0x8000u) & 0xffff0000u;
    return ua | ub;
}
__device__ __forceinline__ float bf_round(float a) {
    unsigned int u = (__builtin_bit_cast(unsigned int, a) + 0x8000u) & 0xffff0000u;
    return __builtin_bit_cast(float, u);
}

// ---------------------------------------------------------------------------
// K1: LN(mask_tokens) -> q -> fold q into Wk. gw packed bf16 pairs [bn][c][4u].
// ---------------------------------------------------------------------------
__global__ __launch_bounds__(256) void k1_prep(
    const float* __restrict__ mt, const float* __restrict__ ln_t_w, const float* __restrict__ ln_t_b,
    const float* __restrict__ ln_p_w, const float* __restrict__ ln_p_b,
    const float* __restrict__ Wq, const float* __restrict__ bq,
    const float* __restrict__ Wk, const float* __restrict__ bk,
    unsigned int* __restrict__ gwp, float* __restrict__ Gv, float* __restrict__ Bc)
{
    int bn  = blockIdx.x;
    int tid = threadIdx.x;
    int wid = tid >> 6, lane = tid & 63;
    __shared__ float nt[C];
    __shared__ float qv[C];
    __shared__ float wks[NH][C];
    __shared__ float red[8];

    float x  = mt[bn * C + tid];
    float s1 = x, s2 = x * x;
    #pragma unroll
    for (int off = 32; off; off >>= 1) {
        s1 += __shfl_xor(s1, off);
        s2 += __shfl_xor(s2, off);
    }
    if (lane == 0) { red[wid] = s1; red[4 + wid] = s2; }
    __syncthreads();
    float mu   = (red[0] + red[1] + red[2] + red[3]) * (1.0f / C);
    float msq  = (red[4] + red[5] + red[6] + red[7]) * (1.0f / C);
    float rstd = rsqrtf(msq - mu * mu + EPS);
    nt[tid] = (x - mu) * rstd * ln_t_w[tid] + ln_t_b[tid];
    __syncthreads();

    {   // q[j=tid] = nt . Wq[j,:] + bq[j]
        float acc = bq[tid];
        const float* wrow = Wq + (size_t)tid * C;
        #pragma unroll 8
        for (int c = 0; c < C; ++c) acc += nt[c] * wrow[c];
        qv[tid] = acc;
    }
    __syncthreads();

    int c = tid;
    #pragma unroll
    for (int h = 0; h < NH; ++h) {
        float a = 0.f;
        #pragma unroll 4
        for (int d = 0; d < 32; ++d) a += qv[h * 32 + d] * Wk[(size_t)(h * 32 + d) * C + c];
        wks[h][c] = a * SCALE;
    }
    __syncthreads();

    for (int i = tid; i < C * 4; i += 256) {
        int cc = i >> 2, pr = i & 3;
        float g0 = ln_p_w[cc] * wks[pr * 2][cc];
        float g1 = ln_p_w[cc] * wks[pr * 2 + 1][cc];
        gwp[(size_t)bn * C * 4 + i] = bf_pack(g0, g1);
    }

    {
        int h = tid >> 5, l32 = tid & 31;
        float g = 0.f, bs = 0.f;
        #pragma unroll
        for (int cc = l32; cc < C; cc += 32) {
            float w = wks[h][cc];
            g  += bf_round(ln_p_w[cc] * w);   // match kattn's unpacked value
            bs += ln_p_b[cc] * w;
        }
        float qb = qv[h * 32 + l32] * bk[h * 32 + l32];
        #pragma unroll
        for (int off = 16; off; off >>= 1) {
            g  += __shfl_xor(g, off);
            bs += __shfl_xor(bs, off);
            qb += __shfl_xor(qb, off);
        }
        if (l32 == 0) {
            Gv[bn * NH + h] = g;
            Bc[bn * NH + h] = bs + qb * SCALE;
        }
    }
}

// ---------------------------------------------------------------------------
// KPASS1 (LINEAR stats sweep): grid 512 = 64 bn x 8 c-chunks(32 rows). Block
// reads 512 KB CONTIGUOUS (32 consecutive c-rows); wave owns an s-quarter, so
// per instruction = 1 KB contiguous and per wave = linear 4 KB runs marching
// through consecutive rows. Chip-wide aggregate stream ~ address-ordered ->
// DRAM page-hit friendly. Computes per-s sum/sq partials only.
// ---------------------------------------------------------------------------
__global__ __launch_bounds__(256, 2) void kpass1(
    const float* __restrict__ pe, float* __restrict__ part)
{
    int blk = blockIdx.x;                 // 512
    int swz = (blk & 7) * 64 + (blk >> 3);
    int bn  = swz >> 3;
    int ch  = swz & 7;
    int tid = threadIdx.x;
    int w = tid >> 6, lane = tid & 63;
    int b = bn >> 3, n = bn & 7;
    const float* xb = pe + ((size_t)(n * 8 + b)) * C * S;
    int c0 = ch * 32;
    int sbase = w * 1024 + lane * 4;

    float sum[16], sq[16];
    #pragma unroll
    for (int i = 0; i < 16; ++i) { sum[i] = 0.f; sq[i] = 0.f; }

    #pragma unroll 4
    for (int r = 0; r < 32; ++r) {
        const float4* row = reinterpret_cast<const float4*>(xb + (size_t)(c0 + r) * S + sbase);
        float4 vv[4];
        vv[0] = row[0];
        vv[1] = row[64];
        vv[2] = row[128];
        vv[3] = row[192];
        #pragma unroll
        for (int i = 0; i < 4; ++i) {
            sum[i*4+0] += vv[i].x; sq[i*4+0] += vv[i].x * vv[i].x;
            sum[i*4+1] += vv[i].y; sq[i*4+1] += vv[i].y * vv[i].y;
            sum[i*4+2] += vv[i].z; sq[i*4+2] += vv[i].z * vv[i].z;
            sum[i*4+3] += vv[i].w; sq[i*4+3] += vv[i].w * vv[i].w;
        }
    }

    float* pp = part + ((size_t)(ch * 64 + bn)) * 2 * S;
    #pragma unroll
    for (int i = 0; i < 4; ++i) {
        int s = w * 1024 + i * 256 + lane * 4;
        *reinterpret_cast<float4*>(pp + s)     = make_float4(sum[i*4+0], sum[i*4+1], sum[i*4+2], sum[i*4+3]);
        *reinterpret_cast<float4*>(pp + S + s) = make_float4(sq[i*4+0],  sq[i*4+1],  sq[i*4+2],  sq[i*4+3]);
    }
}

// ---------------------------------------------------------------------------
// KSTAT: fold 8 chunk partials -> rstd/mur planes [bn][2][S]. Tiny (18 MB).
// ---------------------------------------------------------------------------
__global__ __launch_bounds__(256) void kstat(
    const float* __restrict__ part, float* __restrict__ rm)
{
    int bn  = blockIdx.x;
    int tid = threadIdx.x;
    for (int it = 0; it < 16; ++it) {
        int s = it * 256 + tid;
        float sum = 0.f, sq = 0.f;
        #pragma unroll
        for (int ch = 0; ch < 8; ++ch) {
            const float* pp = part + ((size_t)(ch * 64 + bn)) * 2 * S;
            sum += pp[s];
            sq  += pp[S + s];
        }
        float mu  = sum * (1.f / C);
        float var = sq * (1.f / C) - mu * mu;
        float rs  = rsqrtf(var + EPS);
        rm[(size_t)bn * 2 * S + s]     = rs;
        rm[(size_t)bn * 2 * S + S + s] = mu * rs;
    }
}

// ---------------------------------------------------------------------------
// KATTN (r13 kfused minus stats): grid 1024 = 64 bn x 16 sg(256 s); 4 waves.
// Phase1: lane owns one s; rs/mur loaded from rm; A[8] via 16-deep load
// batches — pe reads now come from the L3 pass-1 just warmed (SRAM: stride-
// tolerant). p -> ptT LDS (bf16) + per-wave LP/ZP. Phase2: MFMA PV, direct Mp.
// ---------------------------------------------------------------------------
__global__ __launch_bounds__(256, 1) void kattn(
    const float* __restrict__ pe, const unsigned int* __restrict__ gwp,
    const float* __restrict__ Gv, const float* __restrict__ Bc,
    const float* __restrict__ rm,
    float* __restrict__ LP, float* __restrict__ ZP, float* __restrict__ Mp)
{
    int blk = blockIdx.x;                    // 1024
    int swz = (blk & 7) * 128 + (blk >> 3);  // XCD-contiguous chunks
    int bn  = swz >> 4;
    int sg  = swz & 15;
    int tid = threadIdx.x;
    int w = tid >> 6, lane = tid & 63;
    int b = bn >> 3, n = bn & 7;
    const float* xb = pe + ((size_t)(n * 8 + b)) * C * S;
    int sgbase = sg * 256;

    __shared__ uint4 gwt[C];                    // 4 KB
    __shared__ unsigned short ptT[16 * PTS];    // 8.5 KB

    {
        const uint4* src = reinterpret_cast<const uint4*>(gwp + (size_t)bn * C * 4);
        for (int i = tid; i < C; i += 256) gwt[i] = src[i];
        for (int i = tid; i < 8 * PTS; i += 256) ptT[8 * PTS + i] = 0;  // rows 8-15
    }
    __syncthreads();

    // ---- phase 1: lane owns s = sgbase + tid ----
    {
        const float* xcol = xb + sgbase + tid;
        float rs   = rm[(size_t)bn * 2 * S + sgbase + tid];
        float murv = rm[(size_t)bn * 2 * S + S + sgbase + tid];

        float A[NH];
        #pragma unroll
        for (int h = 0; h < NH; ++h) A[h] = 0.f;

        for (int cb = 0; cb < C; cb += 16) {
            float xr[16];
            #pragma unroll
            for (int q = 0; q < 16; ++q)
                xr[q] = xcol[(size_t)(cb + q) * S];   // 16 independent loads (L3-hot)
            #pragma unroll
            for (int q = 0; q < 16; ++q) {
                uint4 g = gwt[cb + q];
                float xx = xr[q];
                A[0] += bf_lo(g.x) * xx; A[1] += bf_hi(g.x) * xx;
                A[2] += bf_lo(g.y) * xx; A[3] += bf_hi(g.y) * xx;
                A[4] += bf_lo(g.z) * xx; A[5] += bf_hi(g.z) * xx;
                A[6] += bf_lo(g.w) * xx; A[7] += bf_hi(g.w) * xx;
            }
        }

        #pragma unroll
        for (int h = 0; h < NH; ++h) {
            float p = __expf(rs * A[h] - murv * Gv[bn * NH + h] + Bc[bn * NH + h]); // m=0 (validated)
            ptT[h * PTS + tid] = (unsigned short)(bf_pack(p * rs, 0.f) & 0xffffu);
            float l = p, zz = p * murv;
            #pragma unroll
            for (int off = 32; off; off >>= 1) {
                l  += __shfl_xor(l,  off);
                zz += __shfl_xor(zz, off);
            }
            if (lane == 0) {
                int strip = sg * 4 + w;
                LP[(size_t)(bn * NH + h) * NSTRIP + strip] = l;
                ZP[(size_t)(bn * NH + h) * NSTRIP + strip] = zz;
            }
        }
    }
    __syncthreads();

    // ---- phase 2: MFMA PV, A re-read from block's own (L3-hot) region ----
    {
        int mrow = lane & 15;     // A row within tile; D col (= h)
        int kgrp = lane >> 4;     // k block (8 k each)
        float* mp = Mp + (((size_t)sg * 64 + bn) * C) * NH;
        #pragma unroll
        for (int ct = 0; ct < 4; ++ct) {
            int ctile = w * 4 + ct;
            int crow  = ctile * 16 + mrow;
            const float* arow = xb + (size_t)crow * S + sgbase + kgrp * 8;
            f32x4 acc = {0.f, 0.f, 0.f, 0.f};
            #pragma unroll
            for (int kc = 0; kc < 8; ++kc) {
                float4 a0 = *reinterpret_cast<const float4*>(arow + kc * 32);
                float4 a1 = *reinterpret_cast<const float4*>(arow + kc * 32 + 4);
                uint4 ap;
                ap.x = bf_pack(a0.x, a0.y);
                ap.y = bf_pack(a0.z, a0.w);
                ap.z = bf_pack(a1.x, a1.y);
                ap.w = bf_pack(a1.z, a1.w);
                short8 af = __builtin_bit_cast(short8, ap);
                uint4 bp = *reinterpret_cast<const uint4*>(&ptT[mrow * PTS + kc * 32 + kgrp * 8]);
                short8 bfv = __builtin_bit_cast(short8, bp);
                acc = __builtin_amdgcn_mfma_f32_16x16x32_bf16(af, bfv, acc, 0, 0, 0);
            }
            if (mrow < NH) {
                #pragma unroll
                for (int r = 0; r < 4; ++r) {
                    int cl = ctile * 16 + kgrp * 4 + r;
                    mp[cl * NH + mrow] = acc[r];
                }
            }
        }
    }
}

// ---------------------------------------------------------------------------
// KPOST: per bn: IL/z from 64 strips -> fold 16 Mp partials -> wei (LDS)
// -> ctx -> Wo -> residual -> MLP -> out.
// ---------------------------------------------------------------------------
__global__ __launch_bounds__(256) void kpost(
    const float* __restrict__ mt, const float* __restrict__ Mp,
    const float* __restrict__ LP, const float* __restrict__ ZP,
    const float* __restrict__ lpw, const float* __restrict__ lpb,
    const float* __restrict__ Wv, const float* __restrict__ bv,
    const float* __restrict__ Wo, const float* __restrict__ bo,
    const float* __restrict__ W1, const float* __restrict__ b1,
    const float* __restrict__ W2, const float* __restrict__ b2,
    float* __restrict__ out)
{
    int bn  = blockIdx.x;
    int tid = threadIdx.x;
    __shared__ float ilz[2 * NH];
    __shared__ float wei[NH * C];   // [h][c]
    __shared__ float ctxs[C];
    __shared__ float upds[C];
    __shared__ float hid[2 * C];

    if (tid < NH) {
        float L = 0.f, Z = 0.f;
        #pragma unroll 8
        for (int j = 0; j < NSTRIP; ++j) {
            L += LP[(size_t)(bn * NH + tid) * NSTRIP + j];
            Z += ZP[(size_t)(bn * NH + tid) * NSTRIP + j];
        }
        float inv = 1.f / L;
        ilz[tid]      = inv;
        ilz[NH + tid] = Z * inv;
    }
    __syncthreads();

    for (int v = tid; v < 512; v += 256) {
        int i = v * 4;
        float4 m4 = {0.f, 0.f, 0.f, 0.f};
        #pragma unroll
        for (int sg2 = 0; sg2 < NSG; ++sg2) {
            float4 t = *reinterpret_cast<const float4*>(Mp + ((size_t)sg2 * 64 + bn) * (C * NH) + i);
            m4.x += t.x; m4.y += t.y; m4.z += t.z; m4.w += t.w;
        }
        int c = i >> 3, h0 = i & 7;
        float lw = lpw[c], lb = lpb[c];
        wei[(h0 + 0) * C + c] = lw * (m4.x * ilz[h0 + 0] - ilz[NH + h0 + 0]) + lb;
        wei[(h0 + 1) * C + c] = lw * (m4.y * ilz[h0 + 1] - ilz[NH + h0 + 1]) + lb;
        wei[(h0 + 2) * C + c] = lw * (m4.z * ilz[h0 + 2] - ilz[NH + h0 + 2]) + lb;
        wei[(h0 + 3) * C + c] = lw * (m4.w * ilz[h0 + 3] - ilz[NH + h0 + 3]) + lb;
    }
    __syncthreads();

    {   // ctx[j=tid] = wei[h(j),:] . Wv[j,:] + bv[j]
        int h = tid >> 5;
        float a = bv[tid];
        const float* wrow = Wv + (size_t)tid * C;
        const float* wh   = wei + h * C;
        #pragma unroll 8
        for (int c2 = 0; c2 < C; ++c2) a += wh[c2] * wrow[c2];
        ctxs[tid] = a;
    }
    __syncthreads();

    float att = bo[tid];
    {
        const float* wrow = Wo + (size_t)tid * C;
        #pragma unroll 8
        for (int j = 0; j < C; ++j) att += ctxs[j] * wrow[j];
    }
    float upd = mt[(size_t)bn * C + tid] + att;
    upds[tid] = upd;
    __syncthreads();

    #pragma unroll
    for (int r = 0; r < 2; ++r) {
        int k = tid + r * 256;
        float a = b1[k];
        const float* wrow = W1 + (size_t)k * C;
        #pragma unroll 8
        for (int c2 = 0; c2 < C; ++c2) a += upds[c2] * wrow[c2];
        hid[k] = fmaxf(a, 0.f);
    }
    __syncthreads();

    float a = b2[tid];
    const float* wrow = W2 + (size_t)tid * 2 * C;
    #pragma unroll 8
    for (int k = 0; k < 2 * C; ++k) a += hid[k] * wrow[k];
    out[(size_t)bn * C + tid] = upd + a;
}

extern "C" void kernel_launch(void* const* d_in, const int* in_sizes, int n_in,
                              void* d_out, int out_size, void* d_ws, size_t ws_size,
                              hipStream_t stream)
{
    const float* mt  = (const float*)d_in[0];
    const float* pe  = (const float*)d_in[1];
    const float* ltw = (const float*)d_in[2];
    const float* ltb = (const float*)d_in[3];
    const float* lpw = (const float*)d_in[4];
    const float* lpb = (const float*)d_in[5];
    const float* Wq  = (const float*)d_in[6];
    const float* bq  = (const float*)d_in[7];
    const float* Wk  = (const float*)d_in[8];
    const float* bk  = (const float*)d_in[9];
    const float* Wv  = (const float*)d_in[10];
    const float* bv  = (const float*)d_in[11];
    const float* Wo  = (const float*)d_in[12];
    const float* bo  = (const float*)d_in[13];
    const float* W1  = (const float*)d_in[14];
    const float* b1  = (const float*)d_in[15];
    const float* W2  = (const float*)d_in[16];
    const float* b2  = (const float*)d_in[17];

    float* ws   = (float*)d_ws;
    float* outp = (float*)d_out;

    unsigned int* gwp = (unsigned int*)(ws + OFF_GWP);
    float* Gv         = ws + OFF_G;
    float* Bc         = ws + OFF_BC;
    float* part       = ws + OFF_PART;
    float* rm         = ws + OFF_RM;
    float* LP         = ws + OFF_LP;
    float* ZP         = ws + OFF_ZP;
    float* Mp         = ws + OFF_MP;

    k1_prep<<<64,   256, 0, stream>>>(mt, ltw, ltb, lpw, lpb, Wq, bq, Wk, bk, gwp, Gv, Bc);
    kpass1 <<<512,  256, 0, stream>>>(pe, part);
    kstat  <<<64,   256, 0, stream>>>(part, rm);
    kattn  <<<1024, 256, 0, stream>>>(pe, gwp, Gv, Bc, rm, LP, ZP, Mp);
    kpost  <<<64,   256, 0, stream>>>(mt, Mp, LP, ZP, lpw, lpb, Wv, bv, Wo, bo, W1, b1, W2, b2, outp);
}

// Round 15
// 175.246 us; speedup vs baseline: 1.3820x; 1.3820x over previous
//
#include <hip/hip_runtime.h>
#include <math.h>

#define C 256
#define S 4096
#define NH 8
#define NSG 64        // 64-s groups per bn = Mp partial groups & LP/ZP strips
#define EPS 1e-5f
#define SCALE 0.17677669529663687f   // 1/sqrt(32)

#define TSTR 72       // tile row stride (u16): 144B rows, 16B-aligned, 2-way banks
#define PTSTR 72      // ptT row stride (u16)

// workspace layout (float offsets)
#define OFF_GWP 0                  // 64*256*4 uints = 65536
#define OFF_G   65536              // 512
#define OFF_BC  66048              // 512
#define OFF_LP  66560              // 64*8*64 = 32768
#define OFF_ZP  99328              // 32768
#define OFF_MP  132096             // 64*64*256*8 = 8388608

typedef __attribute__((ext_vector_type(8))) short short8;
typedef __attribute__((ext_vector_type(4))) float f32x4;

__device__ __forceinline__ float bf_lo(unsigned int u) {
    return __builtin_bit_cast(float, u << 16);
}
__device__ __forceinline__ float bf_hi(unsigned int u) {
    return __builtin_bit_cast(float, u & 0xffff0000u);
}
__device__ __forceinline__ unsigned int bf_pack(float a, float b) {
    unsigned int ua = (__builtin_bit_cast(unsigned int, a) + 0x8000u) >> 16;
    unsigned int ub = (__builtin_bit_cast(unsigned int, b) + 0x8000u) & 0xffff0000u;
    return ua | ub;
}
__device__ __forceinline__ float bf_round(float a) {
    unsigned int u = (__builtin_bit_cast(unsigned int, a) + 0x8000u) & 0xffff0000u;
    return __builtin_bit_cast(float, u);
}

// ---------------------------------------------------------------------------
// K1: LN(mask_tokens) -> q -> fold q into Wk. gw packed bf16 pairs [bn][c][4u].
// ---------------------------------------------------------------------------
__global__ __launch_bounds__(256) void k1_prep(
    const float* __restrict__ mt, const float* __restrict__ ln_t_w, const float* __restrict__ ln_t_b,
    const float* __restrict__ ln_p_w, const float* __restrict__ ln_p_b,
    const float* __restrict__ Wq, const float* __restrict__ bq,
    const float* __restrict__ Wk, const float* __restrict__ bk,
    unsigned int* __restrict__ gwp, float* __restrict__ Gv, float* __restrict__ Bc)
{
    int bn  = blockIdx.x;
    int tid = threadIdx.x;
    int wid = tid >> 6, lane = tid & 63;
    __shared__ float nt[C];
    __shared__ float qv[C];
    __shared__ float wks[NH][C];
    __shared__ float red[8];

    float x  = mt[bn * C + tid];
    float s1 = x, s2 = x * x;
    #pragma unroll
    for (int off = 32; off; off >>= 1) {
        s1 += __shfl_xor(s1, off);
        s2 += __shfl_xor(s2, off);
    }
    if (lane == 0) { red[wid] = s1; red[4 + wid] = s2; }
    __syncthreads();
    float mu   = (red[0] + red[1] + red[2] + red[3]) * (1.0f / C);
    float msq  = (red[4] + red[5] + red[6] + red[7]) * (1.0f / C);
    float rstd = rsqrtf(msq - mu * mu + EPS);
    nt[tid] = (x - mu) * rstd * ln_t_w[tid] + ln_t_b[tid];
    __syncthreads();

    {   // q[j=tid] = nt . Wq[j,:] + bq[j]
        float acc = bq[tid];
        const float* wrow = Wq + (size_t)tid * C;
        #pragma unroll 8
        for (int c = 0; c < C; ++c) acc += nt[c] * wrow[c];
        qv[tid] = acc;
    }
    __syncthreads();

    int c = tid;
    #pragma unroll
    for (int h = 0; h < NH; ++h) {
        float a = 0.f;
        #pragma unroll 4
        for (int d = 0; d < 32; ++d) a += qv[h * 32 + d] * Wk[(size_t)(h * 32 + d) * C + c];
        wks[h][c] = a * SCALE;
    }
    __syncthreads();

    for (int i = tid; i < C * 4; i += 256) {
        int cc = i >> 2, pr = i & 3;
        float g0 = ln_p_w[cc] * wks[pr * 2][cc];
        float g1 = ln_p_w[cc] * wks[pr * 2 + 1][cc];
        gwp[(size_t)bn * C * 4 + i] = bf_pack(g0, g1);
    }

    {
        int h = tid >> 5, l32 = tid & 31;
        float g = 0.f, bs = 0.f;
        #pragma unroll
        for (int cc = l32; cc < C; cc += 32) {
            float w = wks[h][cc];
            g  += bf_round(ln_p_w[cc] * w);   // match kfused's unpacked value
            bs += ln_p_b[cc] * w;
        }
        float qb = qv[h * 32 + l32] * bk[h * 32 + l32];
        #pragma unroll
        for (int off = 16; off; off >>= 1) {
            g  += __shfl_xor(g, off);
            bs += __shfl_xor(bs, off);
            qb += __shfl_xor(qb, off);
        }
        if (l32 == 0) {
            Gv[bn * NH + h] = g;
            Bc[bn * NH + h] = bs + qb * SCALE;
        }
    }
}

// ---------------------------------------------------------------------------
// KFUSED v6 (single-touch): grid 4096 = 64 bn x 64 sg(64 s); 4 waves; 3 blk/CU.
// Phase1: thread (w,cg,l16) loads x[c = w*64+4j+cg][s-quad l16*4] (16 float4
// batch, full MLP), packs bf16 into tile[256][TSTR] LDS, accumulates
// sum/sq/A partials; cg-combine via shfl_xor(16,32); pbuf cross-wave.
// Combine (wave 0): stats -> p (m=0 softmax, validated) -> ptT bf16 + LP/ZP.
// Phase2: MFMA PV entirely from LDS (A = tile, B = ptT) -> Mp direct.
// pe is read from global EXACTLY ONCE.
// ---------------------------------------------------------------------------
__global__ __launch_bounds__(256, 3) void kfused(
    const float* __restrict__ pe, const unsigned int* __restrict__ gwp,
    const float* __restrict__ Gv, const float* __restrict__ Bc,
    float* __restrict__ LP, float* __restrict__ ZP, float* __restrict__ Mp)
{
    int blk = blockIdx.x;                     // 4096
    int swz = (blk & 7) * 512 + (blk >> 3);   // XCD-contiguous chunks
    int bn  = swz >> 6;
    int sg  = swz & 63;
    int tid = threadIdx.x;
    int w = tid >> 6, lane = tid & 63;
    int cg = lane >> 4, l16 = lane & 15;
    int b = bn >> 3, n = bn & 7;
    const float* xb = pe + ((size_t)(n * 8 + b)) * C * S;
    int s0 = sg * 64;

    __shared__ unsigned short tile[C * TSTR];   // 36864 B  [c][s] bf16
    __shared__ unsigned short ptT[16 * PTSTR];  // 2304 B   [h][s] bf16 (rows 8-15 zero)
    __shared__ float pbuf[4][64][10];           // 10240 B
    __shared__ uint4 gwt[C];                    // 4096 B

    {
        const uint4* src = reinterpret_cast<const uint4*>(gwp + (size_t)bn * C * 4);
        gwt[tid] = src[tid];
        for (int i = tid; i < 8 * PTSTR; i += 256) ptT[8 * PTSTR + i] = 0;
    }
    __syncthreads();

    // ---- phase 1 ----
    {
        const float* xq = xb + (size_t)(w * 64 + cg) * S + s0 + l16 * 4;
        float4 xr[16];
        #pragma unroll
        for (int j = 0; j < 16; ++j)
            xr[j] = *reinterpret_cast<const float4*>(xq + (size_t)(4 * j) * S);

        float sum[4] = {0.f,0.f,0.f,0.f}, sq[4] = {0.f,0.f,0.f,0.f};
        float A[4][NH];
        #pragma unroll
        for (int e = 0; e < 4; ++e)
            #pragma unroll
            for (int h = 0; h < NH; ++h) A[e][h] = 0.f;

        #pragma unroll
        for (int j = 0; j < 16; ++j) {
            int c = w * 64 + 4 * j + cg;
            uint2 pk;
            pk.x = bf_pack(xr[j].x, xr[j].y);
            pk.y = bf_pack(xr[j].z, xr[j].w);
            *reinterpret_cast<uint2*>(&tile[c * TSTR + l16 * 4]) = pk;
            uint4 g = gwt[c];
            float xe[4] = {xr[j].x, xr[j].y, xr[j].z, xr[j].w};
            #pragma unroll
            for (int e = 0; e < 4; ++e) {
                float xx = xe[e];
                sum[e] += xx;
                sq[e]  += xx * xx;
                A[e][0] += bf_lo(g.x) * xx; A[e][1] += bf_hi(g.x) * xx;
                A[e][2] += bf_lo(g.y) * xx; A[e][3] += bf_hi(g.y) * xx;
                A[e][4] += bf_lo(g.z) * xx; A[e][5] += bf_hi(g.z) * xx;
                A[e][6] += bf_lo(g.w) * xx; A[e][7] += bf_hi(g.w) * xx;
            }
        }
        // cg-combine (lanes sharing l16 across cg hold disjoint c-subsets)
        #pragma unroll
        for (int e = 0; e < 4; ++e) {
            sum[e] += __shfl_xor(sum[e], 16); sum[e] += __shfl_xor(sum[e], 32);
            sq[e]  += __shfl_xor(sq[e],  16); sq[e]  += __shfl_xor(sq[e],  32);
            #pragma unroll
            for (int h = 0; h < NH; ++h) {
                A[e][h] += __shfl_xor(A[e][h], 16);
                A[e][h] += __shfl_xor(A[e][h], 32);
            }
        }
        if (cg == 0) {
            #pragma unroll
            for (int e = 0; e < 4; ++e) {
                float* pb = &pbuf[w][l16 * 4 + e][0];
                pb[0] = sum[e];
                pb[1] = sq[e];
                #pragma unroll
                for (int h = 0; h < NH; ++h) pb[2 + h] = A[e][h];
            }
        }
    }
    __syncthreads();

    // ---- combine: wave 0, thread = s ----
    if (tid < 64) {
        int s = tid;
        float sum = 0.f, sq = 0.f;
        float A[NH];
        #pragma unroll
        for (int h = 0; h < NH; ++h) A[h] = 0.f;
        #pragma unroll
        for (int wv = 0; wv < 4; ++wv) {
            const float* pb = &pbuf[wv][s][0];
            sum += pb[0];
            sq  += pb[1];
            #pragma unroll
            for (int h = 0; h < NH; ++h) A[h] += pb[2 + h];
        }
        float mu   = sum * (1.f / C);
        float var  = sq * (1.f / C) - mu * mu;
        float rs   = rsqrtf(var + EPS);
        float murv = mu * rs;

        float l8[NH], z8[NH];
        #pragma unroll
        for (int h = 0; h < NH; ++h) {
            float p = __expf(rs * A[h] - murv * Gv[bn * NH + h] + Bc[bn * NH + h]);
            ptT[h * PTSTR + s] = (unsigned short)(bf_pack(p * rs, 0.f) & 0xffffu);
            l8[h] = p;
            z8[h] = p * murv;
        }
        #pragma unroll
        for (int h = 0; h < NH; ++h) {
            float l = l8[h], zz = z8[h];
            #pragma unroll
            for (int off = 32; off; off >>= 1) {
                l  += __shfl_xor(l,  off);
                zz += __shfl_xor(zz, off);
            }
            if (tid == 0) {
                LP[(size_t)(bn * NH + h) * NSG + sg] = l;
                ZP[(size_t)(bn * NH + h) * NSG + sg] = zz;
            }
        }
    }
    __syncthreads();

    // ---- phase 2: MFMA PV, all operands from LDS ----
    {
        int mrow = lane & 15;     // A row-id bits; D col (= h)
        int kgrp = lane >> 4;     // k block (8 k each)
        float* mp = Mp + (((size_t)sg * 64 + bn) * C) * NH;
        #pragma unroll
        for (int ct = 0; ct < 4; ++ct) {
            int ctile = w * 4 + ct;
            int crow  = ctile * 16 + mrow;
            f32x4 acc = {0.f, 0.f, 0.f, 0.f};
            #pragma unroll
            for (int kc = 0; kc < 2; ++kc) {
                uint4 ap = *reinterpret_cast<const uint4*>(&tile[crow * TSTR + kc * 32 + kgrp * 8]);
                uint4 bp = *reinterpret_cast<const uint4*>(&ptT[mrow * PTSTR + kc * 32 + kgrp * 8]);
                short8 af  = __builtin_bit_cast(short8, ap);
                short8 bfv = __builtin_bit_cast(short8, bp);
                acc = __builtin_amdgcn_mfma_f32_16x16x32_bf16(af, bfv, acc, 0, 0, 0);
            }
            if (mrow < NH) {
                #pragma unroll
                for (int r = 0; r < 4; ++r) {
                    int cl = ctile * 16 + kgrp * 4 + r;
                    mp[cl * NH + mrow] = acc[r];
                }
            }
        }
    }
}

// ---------------------------------------------------------------------------
// KPOST: per bn: IL/z from 64 strips -> fold 64 Mp partials -> wei (LDS)
// -> ctx -> Wo -> residual -> MLP -> out. Per-thread serial-K GEMVs.
// ---------------------------------------------------------------------------
__global__ __launch_bounds__(256) void kpost(
    const float* __restrict__ mt, const float* __restrict__ Mp,
    const float* __restrict__ LP, const float* __restrict__ ZP,
    const float* __restrict__ lpw, const float* __restrict__ lpb,
    const float* __restrict__ Wv, const float* __restrict__ bv,
    const float* __restrict__ Wo, const float* __restrict__ bo,
    const float* __restrict__ W1, const float* __restrict__ b1,
    const float* __restrict__ W2, const float* __restrict__ b2,
    float* __restrict__ out)
{
    int bn  = blockIdx.x;
    int tid = threadIdx.x;
    __shared__ float ilz[2 * NH];
    __shared__ float wei[NH * C];   // [h][c]
    __shared__ float ctxs[C];
    __shared__ float upds[C];
    __shared__ float hid[2 * C];

    if (tid < NH) {
        float L = 0.f, Z = 0.f;
        #pragma unroll 8
        for (int j = 0; j < NSG; ++j) {
            L += LP[(size_t)(bn * NH + tid) * NSG + j];
            Z += ZP[(size_t)(bn * NH + tid) * NSG + j];
        }
        float inv = 1.f / L;
        ilz[tid]      = inv;
        ilz[NH + tid] = Z * inv;
    }
    __syncthreads();

    for (int v = tid; v < 512; v += 256) {
        int i = v * 4;
        float4 m4 = {0.f, 0.f, 0.f, 0.f};
        #pragma unroll 8
        for (int sg2 = 0; sg2 < NSG; ++sg2) {
            float4 t = *reinterpret_cast<const float4*>(Mp + ((size_t)sg2 * 64 + bn) * (C * NH) + i);
            m4.x += t.x; m4.y += t.y; m4.z += t.z; m4.w += t.w;
        }
        int c = i >> 3, h0 = i & 7;
        float lw = lpw[c], lb = lpb[c];
        wei[(h0 + 0) * C + c] = lw * (m4.x * ilz[h0 + 0] - ilz[NH + h0 + 0]) + lb;
        wei[(h0 + 1) * C + c] = lw * (m4.y * ilz[h0 + 1] - ilz[NH + h0 + 1]) + lb;
        wei[(h0 + 2) * C + c] = lw * (m4.z * ilz[h0 + 2] - ilz[NH + h0 + 2]) + lb;
        wei[(h0 + 3) * C + c] = lw * (m4.w * ilz[h0 + 3] - ilz[NH + h0 + 3]) + lb;
    }
    __syncthreads();

    {   // ctx[j=tid] = wei[h(j),:] . Wv[j,:] + bv[j]
        int h = tid >> 5;
        float a = bv[tid];
        const float* wrow = Wv + (size_t)tid * C;
        const float* wh   = wei + h * C;
        #pragma unroll 16
        for (int c2 = 0; c2 < C; ++c2) a += wh[c2] * wrow[c2];
        ctxs[tid] = a;
    }
    __syncthreads();

    float att = bo[tid];
    {
        const float* wrow = Wo + (size_t)tid * C;
        #pragma unroll 16
        for (int j = 0; j < C; ++j) att += ctxs[j] * wrow[j];
    }
    float upd = mt[(size_t)bn * C + tid] + att;
    upds[tid] = upd;
    __syncthreads();

    #pragma unroll
    for (int r = 0; r < 2; ++r) {
        int k = tid + r * 256;
        float a = b1[k];
        const float* wrow = W1 + (size_t)k * C;
        #pragma unroll 16
        for (int c2 = 0; c2 < C; ++c2) a += upds[c2] * wrow[c2];
        hid[k] = fmaxf(a, 0.f);
    }
    __syncthreads();

    float a = b2[tid];
    const float* wrow = W2 + (size_t)tid * 2 * C;
    #pragma unroll 16
    for (int k = 0; k < 2 * C; ++k) a += hid[k] * wrow[k];
    out[(size_t)bn * C + tid] = upd + a;
}

extern "C" void kernel_launch(void* const* d_in, const int* in_sizes, int n_in,
                              void* d_out, int out_size, void* d_ws, size_t ws_size,
                              hipStream_t stream)
{
    const float* mt  = (const float*)d_in[0];
    const float* pe  = (const float*)d_in[1];
    const float* ltw = (const float*)d_in[2];
    const float* ltb = (const float*)d_in[3];
    const float* lpw = (const float*)d_in[4];
    const float* lpb = (const float*)d_in[5];
    const float* Wq  = (const float*)d_in[6];
    const float* bq  = (const float*)d_in[7];
    const float* Wk  = (const float*)d_in[8];
    const float* bk  = (const float*)d_in[9];
    const float* Wv  = (const float*)d_in[10];
    const float* bv  = (const float*)d_in[11];
    const float* Wo  = (const float*)d_in[12];
    const float* bo  = (const float*)d_in[13];
    const float* W1  = (const float*)d_in[14];
    const float* b1  = (const float*)d_in[15];
    const float* W2  = (const float*)d_in[16];
    const float* b2  = (const float*)d_in[17];

    float* ws   = (float*)d_ws;
    float* outp = (float*)d_out;

    unsigned int* gwp = (unsigned int*)(ws + OFF_GWP);
    float* Gv         = ws + OFF_G;
    float* Bc         = ws + OFF_BC;
    float* LP         = ws + OFF_LP;
    float* ZP         = ws + OFF_ZP;
    float* Mp         = ws + OFF_MP;

    k1_prep<<<64,   256, 0, stream>>>(mt, ltw, ltb, lpw, lpb, Wq, bq, Wk, bk, gwp, Gv, Bc);
    kfused <<<4096, 256, 0, stream>>>(pe, gwp, Gv, Bc, LP, ZP, Mp);
    kpost  <<<64,   256, 0, stream>>>(mt, Mp, LP, ZP, lpw, lpb, Wv, bv, Wo, bo, W1, b1, W2, b2, outp);
}

// Round 17
// 147.831 us; speedup vs baseline: 1.6383x; 1.1855x over previous
//
#include <hip/hip_runtime.h>
#include <math.h>

#define C 256
#define S 4096
#define NH 8
#define NSG 64        // 64-s groups per bn = Mp partial groups & LP/ZP strips
#define EPS 1e-5f
#define SCALE 0.17677669529663687f   // 1/sqrt(32)

#define TSTR 72       // tile row stride (u16): 144B rows, 16B-aligned, 2-way banks
#define PTSTR 72      // ptT row stride (u16)

// workspace layout (float offsets)
#define OFF_GWP 0                  // 64*256*4 uints = 65536
#define OFF_G   65536              // 512
#define OFF_BC  66048              // 512
#define OFF_LP  66560              // 64*8*64 = 32768
#define OFF_ZP  99328              // 32768
#define OFF_WEI 132096             // 64*8*256 = 131072
#define OFF_MP  263168             // 64*64*256*8 = 8388608

typedef __attribute__((ext_vector_type(8))) short short8;
typedef __attribute__((ext_vector_type(4))) float f32x4;
typedef __attribute__((ext_vector_type(4))) float nfloat4;   // native clang vector (nt-load ok)

__device__ __forceinline__ float bf_lo(unsigned int u) {
    return __builtin_bit_cast(float, u << 16);
}
__device__ __forceinline__ float bf_hi(unsigned int u) {
    return __builtin_bit_cast(float, u & 0xffff0000u);
}
__device__ __forceinline__ unsigned int bf_pack(float a, float b) {
    unsigned int ua = (__builtin_bit_cast(unsigned int, a) + 0x8000u) >> 16;
    unsigned int ub = (__builtin_bit_cast(unsigned int, b) + 0x8000u) & 0xffff0000u;
    return ua | ub;
}
__device__ __forceinline__ float bf_round(float a) {
    unsigned int u = (__builtin_bit_cast(unsigned int, a) + 0x8000u) & 0xffff0000u;
    return __builtin_bit_cast(float, u);
}

// ---------------------------------------------------------------------------
// K1: LN(mask_tokens) -> q -> fold q into Wk. gw packed bf16 pairs [bn][c][4u].
// ---------------------------------------------------------------------------
__global__ __launch_bounds__(256) void k1_prep(
    const float* __restrict__ mt, const float* __restrict__ ln_t_w, const float* __restrict__ ln_t_b,
    const float* __restrict__ ln_p_w, const float* __restrict__ ln_p_b,
    const float* __restrict__ Wq, const float* __restrict__ bq,
    const float* __restrict__ Wk, const float* __restrict__ bk,
    unsigned int* __restrict__ gwp, float* __restrict__ Gv, float* __restrict__ Bc)
{
    int bn  = blockIdx.x;
    int tid = threadIdx.x;
    int wid = tid >> 6, lane = tid & 63;
    __shared__ float nt[C];
    __shared__ float qv[C];
    __shared__ float wks[NH][C];
    __shared__ float red[8];

    float x  = mt[bn * C + tid];
    float s1 = x, s2 = x * x;
    #pragma unroll
    for (int off = 32; off; off >>= 1) {
        s1 += __shfl_xor(s1, off);
        s2 += __shfl_xor(s2, off);
    }
    if (lane == 0) { red[wid] = s1; red[4 + wid] = s2; }
    __syncthreads();
    float mu   = (red[0] + red[1] + red[2] + red[3]) * (1.0f / C);
    float msq  = (red[4] + red[5] + red[6] + red[7]) * (1.0f / C);
    float rstd = rsqrtf(msq - mu * mu + EPS);
    nt[tid] = (x - mu) * rstd * ln_t_w[tid] + ln_t_b[tid];
    __syncthreads();

    {   // q[j=tid] = nt . Wq[j,:] + bq[j]
        float acc = bq[tid];
        const float* wrow = Wq + (size_t)tid * C;
        #pragma unroll 8
        for (int c = 0; c < C; ++c) acc += nt[c] * wrow[c];
        qv[tid] = acc;
    }
    __syncthreads();

    int c = tid;
    #pragma unroll
    for (int h = 0; h < NH; ++h) {
        float a = 0.f;
        #pragma unroll 4
        for (int d = 0; d < 32; ++d) a += qv[h * 32 + d] * Wk[(size_t)(h * 32 + d) * C + c];
        wks[h][c] = a * SCALE;
    }
    __syncthreads();

    for (int i = tid; i < C * 4; i += 256) {
        int cc = i >> 2, pr = i & 3;
        float g0 = ln_p_w[cc] * wks[pr * 2][cc];
        float g1 = ln_p_w[cc] * wks[pr * 2 + 1][cc];
        gwp[(size_t)bn * C * 4 + i] = bf_pack(g0, g1);
    }

    {
        int h = tid >> 5, l32 = tid & 31;
        float g = 0.f, bs = 0.f;
        #pragma unroll
        for (int cc = l32; cc < C; cc += 32) {
            float w = wks[h][cc];
            g  += bf_round(ln_p_w[cc] * w);   // match kfused's unpacked value
            bs += ln_p_b[cc] * w;
        }
        float qb = qv[h * 32 + l32] * bk[h * 32 + l32];
        #pragma unroll
        for (int off = 16; off; off >>= 1) {
            g  += __shfl_xor(g, off);
            bs += __shfl_xor(bs, off);
            qb += __shfl_xor(qb, off);
        }
        if (l32 == 0) {
            Gv[bn * NH + h] = g;
            Bc[bn * NH + h] = bs + qb * SCALE;
        }
    }
}

// ---------------------------------------------------------------------------
// KFUSED v6.1 (single-touch + nontemporal): grid 4096 = 64 bn x 64 sg(64 s);
// 4 waves; 3 blk/CU. pe loads marked NONTEMPORAL (read-once, skip L2 keep),
// via native ext_vector_type float4 (HIP_vector_type rejected by builtin).
// Phase1: (w,cg,l16) loads 16 float4, packs bf16 tile + stats partials;
// cg-combine shfl_xor(16,32); pbuf cross-wave. Combine (wave0): stats -> p
// (m=0 softmax) -> ptT + LP/ZP. Phase2: MFMA PV from LDS -> Mp direct.
// ---------------------------------------------------------------------------
__global__ __launch_bounds__(256, 3) void kfused(
    const float* __restrict__ pe, const unsigned int* __restrict__ gwp,
    const float* __restrict__ Gv, const float* __restrict__ Bc,
    float* __restrict__ LP, float* __restrict__ ZP, float* __restrict__ Mp)
{
    int blk = blockIdx.x;                     // 4096
    int swz = (blk & 7) * 512 + (blk >> 3);   // XCD-contiguous chunks
    int bn  = swz >> 6;
    int sg  = swz & 63;
    int tid = threadIdx.x;
    int w = tid >> 6, lane = tid & 63;
    int cg = lane >> 4, l16 = lane & 15;
    int b = bn >> 3, n = bn & 7;
    const float* xb = pe + ((size_t)(n * 8 + b)) * C * S;
    int s0 = sg * 64;

    __shared__ unsigned short tile[C * TSTR];   // 36864 B  [c][s] bf16
    __shared__ unsigned short ptT[16 * PTSTR];  // 2304 B   [h][s] bf16 (rows 8-15 zero)
    __shared__ float pbuf[4][64][10];           // 10240 B
    __shared__ uint4 gwt[C];                    // 4096 B

    {
        const uint4* src = reinterpret_cast<const uint4*>(gwp + (size_t)bn * C * 4);
        gwt[tid] = src[tid];
        for (int i = tid; i < 8 * PTSTR; i += 256) ptT[8 * PTSTR + i] = 0;
    }
    __syncthreads();

    // ---- phase 1 ----
    {
        const float* xq = xb + (size_t)(w * 64 + cg) * S + s0 + l16 * 4;
        nfloat4 xr[16];
        #pragma unroll
        for (int j = 0; j < 16; ++j)
            xr[j] = __builtin_nontemporal_load(
                        reinterpret_cast<const nfloat4*>(xq + (size_t)(4 * j) * S));

        float sum[4] = {0.f,0.f,0.f,0.f}, sq[4] = {0.f,0.f,0.f,0.f};
        float A[4][NH];
        #pragma unroll
        for (int e = 0; e < 4; ++e)
            #pragma unroll
            for (int h = 0; h < NH; ++h) A[e][h] = 0.f;

        #pragma unroll
        for (int j = 0; j < 16; ++j) {
            int c = w * 64 + 4 * j + cg;
            uint2 pk;
            pk.x = bf_pack(xr[j].x, xr[j].y);
            pk.y = bf_pack(xr[j].z, xr[j].w);
            *reinterpret_cast<uint2*>(&tile[c * TSTR + l16 * 4]) = pk;
            uint4 g = gwt[c];
            float xe[4] = {xr[j].x, xr[j].y, xr[j].z, xr[j].w};
            #pragma unroll
            for (int e = 0; e < 4; ++e) {
                float xx = xe[e];
                sum[e] += xx;
                sq[e]  += xx * xx;
                A[e][0] += bf_lo(g.x) * xx; A[e][1] += bf_hi(g.x) * xx;
                A[e][2] += bf_lo(g.y) * xx; A[e][3] += bf_hi(g.y) * xx;
                A[e][4] += bf_lo(g.z) * xx; A[e][5] += bf_hi(g.z) * xx;
                A[e][6] += bf_lo(g.w) * xx; A[e][7] += bf_hi(g.w) * xx;
            }
        }
        // cg-combine (lanes sharing l16 across cg hold disjoint c-subsets)
        #pragma unroll
        for (int e = 0; e < 4; ++e) {
            sum[e] += __shfl_xor(sum[e], 16); sum[e] += __shfl_xor(sum[e], 32);
            sq[e]  += __shfl_xor(sq[e],  16); sq[e]  += __shfl_xor(sq[e],  32);
            #pragma unroll
            for (int h = 0; h < NH; ++h) {
                A[e][h] += __shfl_xor(A[e][h], 16);
                A[e][h] += __shfl_xor(A[e][h], 32);
            }
        }
        if (cg == 0) {
            #pragma unroll
            for (int e = 0; e < 4; ++e) {
                float* pb = &pbuf[w][l16 * 4 + e][0];
                pb[0] = sum[e];
                pb[1] = sq[e];
                #pragma unroll
                for (int h = 0; h < NH; ++h) pb[2 + h] = A[e][h];
            }
        }
    }
    __syncthreads();

    // ---- combine: wave 0, thread = s ----
    if (tid < 64) {
        int s = tid;
        float sum = 0.f, sq = 0.f;
        float A[NH];
        #pragma unroll
        for (int h = 0; h < NH; ++h) A[h] = 0.f;
        #pragma unroll
        for (int wv = 0; wv < 4; ++wv) {
            const float* pb = &pbuf[wv][s][0];
            sum += pb[0];
            sq  += pb[1];
            #pragma unroll
            for (int h = 0; h < NH; ++h) A[h] += pb[2 + h];
        }
        float mu   = sum * (1.f / C);
        float var  = sq * (1.f / C) - mu * mu;
        float rs   = rsqrtf(var + EPS);
        float murv = mu * rs;

        float l8[NH], z8[NH];
        #pragma unroll
        for (int h = 0; h < NH; ++h) {
            float p = __expf(rs * A[h] - murv * Gv[bn * NH + h] + Bc[bn * NH + h]);
            ptT[h * PTSTR + s] = (unsigned short)(bf_pack(p * rs, 0.f) & 0xffffu);
            l8[h] = p;
            z8[h] = p * murv;
        }
        #pragma unroll
        for (int h = 0; h < NH; ++h) {
            float l = l8[h], zz = z8[h];
            #pragma unroll
            for (int off = 32; off; off >>= 1) {
                l  += __shfl_xor(l,  off);
                zz += __shfl_xor(zz, off);
            }
            if (tid == 0) {
                LP[(size_t)(bn * NH + h) * NSG + sg] = l;
                ZP[(size_t)(bn * NH + h) * NSG + sg] = zz;
            }
        }
    }
    __syncthreads();

    // ---- phase 2: MFMA PV, all operands from LDS ----
    {
        int mrow = lane & 15;     // A row-id bits; D col (= h)
        int kgrp = lane >> 4;     // k block (8 k each)
        float* mp = Mp + (((size_t)sg * 64 + bn) * C) * NH;
        #pragma unroll
        for (int ct = 0; ct < 4; ++ct) {
            int ctile = w * 4 + ct;
            int crow  = ctile * 16 + mrow;
            f32x4 acc = {0.f, 0.f, 0.f, 0.f};
            #pragma unroll
            for (int kc = 0; kc < 2; ++kc) {
                uint4 ap = *reinterpret_cast<const uint4*>(&tile[crow * TSTR + kc * 32 + kgrp * 8]);
                uint4 bp = *reinterpret_cast<const uint4*>(&ptT[mrow * PTSTR + kc * 32 + kgrp * 8]);
                short8 af  = __builtin_bit_cast(short8, ap);
                short8 bfv = __builtin_bit_cast(short8, bp);
                acc = __builtin_amdgcn_mfma_f32_16x16x32_bf16(af, bfv, acc, 0, 0, 0);
            }
            if (mrow < NH) {
                #pragma unroll
                for (int r = 0; r < 4; ++r) {
                    int cl = ctile * 16 + kgrp * 4 + r;
                    mp[cl * NH + mrow] = acc[r];
                }
            }
        }
    }
}

// ---------------------------------------------------------------------------
// KFOLDM: grid 512 = 64 bn x 8 c-slices(32). Thread = (c_local, h).
// Per sg iteration the block reads 1 KB CONTIGUOUS of Mp (coalesced);
// 64 iterations, unroll 8 (8 loads in flight). Applies IL/z/ln_p -> wei.
// ---------------------------------------------------------------------------
__global__ __launch_bounds__(256) void kfoldM(
    const float* __restrict__ Mp, const float* __restrict__ LP, const float* __restrict__ ZP,
    const float* __restrict__ lpw, const float* __restrict__ lpb, float* __restrict__ weig)
{
    int blk = blockIdx.x;
    int bn = blk >> 3, slice = blk & 7;
    int tid = threadIdx.x;
    __shared__ float ilz[2 * NH];

    if (tid < NH) {
        float L = 0.f, Z = 0.f;
        #pragma unroll 8
        for (int j = 0; j < NSG; ++j) {
            L += LP[(size_t)(bn * NH + tid) * NSG + j];
            Z += ZP[(size_t)(bn * NH + tid) * NSG + j];
        }
        float inv = 1.f / L;
        ilz[tid]      = inv;
        ilz[NH + tid] = Z * inv;
    }
    __syncthreads();

    int c0 = slice * 32;
    const float* base = Mp + ((size_t)bn * C + c0) * NH + tid;
    float acc = 0.f;
    #pragma unroll 8
    for (int sg = 0; sg < NSG; ++sg)
        acc += base[(size_t)sg * 64 * C * NH];

    int c = c0 + (tid >> 3), h = tid & 7;
    weig[(size_t)bn * NH * C + h * C + c] = lpw[c] * (acc * ilz[h] - ilz[NH + h]) + lpb[c];
}

// ---------------------------------------------------------------------------
// KPOST: per bn: wei (global, 2 KB) -> ctx -> Wo -> residual -> MLP -> out.
// Per-thread serial-K GEMVs (L2-hot weight rows, ILP loads).
// ---------------------------------------------------------------------------
__global__ __launch_bounds__(256) void kpost(
    const float* __restrict__ mt, const float* __restrict__ weig,
    const float* __restrict__ Wv, const float* __restrict__ bv,
    const float* __restrict__ Wo, const float* __restrict__ bo,
    const float* __restrict__ W1, const float* __restrict__ b1,
    const float* __restrict__ W2, const float* __restrict__ b2,
    float* __restrict__ out)
{
    int bn  = blockIdx.x;
    int tid = threadIdx.x;
    __shared__ float wei[NH * C];   // [h][c]
    __shared__ float ctxs[C];
    __shared__ float upds[C];
    __shared__ float hid[2 * C];

    for (int v = tid; v < 512; v += 256)
        *reinterpret_cast<float4*>(&wei[v * 4]) =
            *reinterpret_cast<const float4*>(weig + (size_t)bn * NH * C + v * 4);
    __syncthreads();

    {   // ctx[j=tid] = wei[h(j),:] . Wv[j,:] + bv[j]
        int h = tid >> 5;
        float a = bv[tid];
        const float* wrow = Wv + (size_t)tid * C;
        const float* wh   = wei + h * C;
        #pragma unroll 16
        for (int c2 = 0; c2 < C; ++c2) a += wh[c2] * wrow[c2];
        ctxs[tid] = a;
    }
    __syncthreads();

    float att = bo[tid];
    {
        const float* wrow = Wo + (size_t)tid * C;
        #pragma unroll 16
        for (int j = 0; j < C; ++j) att += ctxs[j] * wrow[j];
    }
    float upd = mt[(size_t)bn * C + tid] + att;
    upds[tid] = upd;
    __syncthreads();

    #pragma unroll
    for (int r = 0; r < 2; ++r) {
        int k = tid + r * 256;
        float a = b1[k];
        const float* wrow = W1 + (size_t)k * C;
        #pragma unroll 16
        for (int c2 = 0; c2 < C; ++c2) a += upds[c2] * wrow[c2];
        hid[k] = fmaxf(a, 0.f);
    }
    __syncthreads();

    float a = b2[tid];
    const float* wrow = W2 + (size_t)tid * 2 * C;
    #pragma unroll 16
    for (int k = 0; k < 2 * C; ++k) a += hid[k] * wrow[k];
    out[(size_t)bn * C + tid] = upd + a;
}

extern "C" void kernel_launch(void* const* d_in, const int* in_sizes, int n_in,
                              void* d_out, int out_size, void* d_ws, size_t ws_size,
                              hipStream_t stream)
{
    const float* mt  = (const float*)d_in[0];
    const float* pe  = (const float*)d_in[1];
    const float* ltw = (const float*)d_in[2];
    const float* ltb = (const float*)d_in[3];
    const float* lpw = (const float*)d_in[4];
    const float* lpb = (const float*)d_in[5];
    const float* Wq  = (const float*)d_in[6];
    const float* bq  = (const float*)d_in[7];
    const float* Wk  = (const float*)d_in[8];
    const float* bk  = (const float*)d_in[9];
    const float* Wv  = (const float*)d_in[10];
    const float* bv  = (const float*)d_in[11];
    const float* Wo  = (const float*)d_in[12];
    const float* bo  = (const float*)d_in[13];
    const float* W1  = (const float*)d_in[14];
    const float* b1  = (const float*)d_in[15];
    const float* W2  = (const float*)d_in[16];
    const float* b2  = (const float*)d_in[17];

    float* ws   = (float*)d_ws;
    float* outp = (float*)d_out;

    unsigned int* gwp = (unsigned int*)(ws + OFF_GWP);
    float* Gv         = ws + OFF_G;
    float* Bc         = ws + OFF_BC;
    float* LP         = ws + OFF_LP;
    float* ZP         = ws + OFF_ZP;
    float* weig       = ws + OFF_WEI;
    float* Mp         = ws + OFF_MP;

    k1_prep<<<64,   256, 0, stream>>>(mt, ltw, ltb, lpw, lpb, Wq, bq, Wk, bk, gwp, Gv, Bc);
    kfused <<<4096, 256, 0, stream>>>(pe, gwp, Gv, Bc, LP, ZP, Mp);
    kfoldM <<<512,  256, 0, stream>>>(Mp, LP, ZP, lpw, lpb, weig);
    kpost  <<<64,   256, 0, stream>>>(mt, weig, Wv, bv, Wo, bo, W1, b1, W2, b2, outp);
}